// Round 13
// baseline (35.040 us; speedup 1.0000x reference)
//
#include <hip/hip_runtime.h>

#define NCLS 256
#define NDF  512
#define BSZ  1024
#define ALP  0.1f

// score[b,c] = s1[b,c]-s1[b,t] + 0.5*ALP*(R[t,c]-R[t,t]),  t=gt[b]
// Two dispatches (kernel boundary = the only cheap cross-XCD fence here;
// R4/R5/R10/R11: every in-kernel cross-block sync costs 2-5x).
// R13: k1 = R12's (128 blk x 512 thr: R slabs waves 0-3 + bias1 waves 4-7).
//      k2 = LDS-FREE s1 GEMM: each lane loads its MFMA fragments directly
//      from global (same m89-verified layout the LDS tiles delivered), packs
//      in-register, 16 MFMA in 2 chains, fused fold epilogue. Zero barriers,
//      zero LDS, zero bank conflicts in k2 -> tests whether k2's ~10us was
//      the stage/pack/barrier chain (expect ~20-22us) or structural launch
//      floor (expect flat ~25us -> conclude).
// MFMA mapping m89/m97-verified, r6-r12-validated (absmax 1.0).

typedef __attribute__((ext_vector_type(8))) short bf16x8;
typedef __attribute__((ext_vector_type(4))) float f32x4;

__device__ __forceinline__ unsigned rne_pk(float lo, float hi) {
    union { float f; unsigned u; } a, b;
    a.f = lo; b.f = hi;
    unsigned ua = (a.u + 0x7FFFu + ((a.u >> 16) & 1u)) >> 16;
    unsigned ub = (b.u + 0x7FFFu + ((b.u >> 16) & 1u)) & 0xFFFF0000u;
    return ua | ub;
}
__device__ __forceinline__ uint4 pk16(float4 p, float4 q) {
    uint4 r;
    r.x = rne_pk(p.x, p.y); r.y = rne_pk(p.z, p.w);
    r.z = rne_pk(q.x, q.y); r.w = rne_pk(q.z, q.w);
    return r;
}
__device__ __forceinline__ bf16x8 pkfrag(float4 p, float4 q) {
    return __builtin_bit_cast(bf16x8, pk16(p, q));
}
__device__ __forceinline__ float bf16r(float x) {
    union { float f; unsigned u; } c; c.f = x;
    c.u = (c.u + 0x7FFFu + ((c.u >> 16) & 1u)) & 0xFFFF0000u;
    return c.f;
}

// ---------------------------------------------------------------------------
// Kernel 1 (unchanged from R12): 128 blocks x 512 threads.
//  waves 0-3 (tid<256): R slab partial: z=bid&7, tile=bid>>3: bm=tile&3, bn=tile>>2.
//  waves 4-7: bias1[bid*8 + (wv-4)*2 + (lane>>5)] = bf16-rounded dot(df_b, fc_t).
__global__ __launch_bounds__(512) void k1_R_bias(const float* __restrict__ df,
                                                 const int* __restrict__ gt,
                                                 const float* __restrict__ fc,
                                                 float* __restrict__ Rp,
                                                 float* __restrict__ bias1) {
    __shared__ union {
        struct { alignas(16) char A[64 * 256]; alignas(16) char B[64 * 256]; } g;
        struct { int gts[BSZ]; unsigned long long bmap[64 * 16]; } r;
    } sm;

    const int tid = threadIdx.x;
    const int bid = blockIdx.x;
    const int lane = tid & 63;
    const int wv = tid >> 6;

    for (int i = tid; i < BSZ; i += 512) sm.r.gts[i] = gt[i];
    for (int i = tid; i < 1024; i += 512) sm.r.bmap[i] = 0ull;
    __syncthreads();                                   // S1
    for (int i = tid; i < BSZ; i += 512) {
        const int c = sm.r.gts[i] - ((bid >> 3) & 3) * 64;
        if ((unsigned)c < 64u) atomicOr(&sm.r.bmap[c * 16 + (i >> 6)], 1ull << (i & 63));
    }

    const int z = bid & 7;
    const int tile = bid >> 3;
    const int bm = tile & 3, bn = tile >> 2;
    const int D0 = z * 64;
    const int sr = tid >> 2;
    const int sswz = (sr & 7) << 4;
    const int clocal = sr;
    const int myclass = bm * 64 + (clocal & 63);
    const int dim0 = D0 + (tid & 3) * 16;
    const int kbl = (tid & 3) * 32;
    const int kbq = 128 + kbl;

    float fcq[16];
    float4 b0, b1, b2, b3;
    int bsample = 0, bt = 0;
    if (wv < 4) {
        const float* Bg = fc + (bn * 64 + sr) * NDF + dim0;
        b0 = ((const float4*)Bg)[0]; b1 = ((const float4*)Bg)[1];
        b2 = ((const float4*)Bg)[2]; b3 = ((const float4*)Bg)[3];
        const float* fct = fc + myclass * NDF + dim0;
        const float4 q0 = ((const float4*)fct)[0], q1 = ((const float4*)fct)[1];
        const float4 q2 = ((const float4*)fct)[2], q3 = ((const float4*)fct)[3];
        fcq[0]=q0.x; fcq[1]=q0.y; fcq[2]=q0.z; fcq[3]=q0.w;
        fcq[4]=q1.x; fcq[5]=q1.y; fcq[6]=q1.z; fcq[7]=q1.w;
        fcq[8]=q2.x; fcq[9]=q2.y; fcq[10]=q2.z; fcq[11]=q2.w;
        fcq[12]=q3.x; fcq[13]=q3.y; fcq[14]=q3.z; fcq[15]=q3.w;
    } else {
        bsample = bid * 8 + (wv - 4) * 2 + (lane >> 5);
        bt = sm.r.gts[bsample];
    }
    __syncthreads();                                   // S2

    float m[16], v[16];
    if (wv < 4) {
#pragma unroll
        for (int j = 0; j < 16; ++j) { m[j] = 0.f; v[j] = 0.f; }
        float nf = 0.f;
        int w = 0;
        unsigned long long bits = sm.r.bmap[clocal * 16];
        auto next = [&]() -> int {
            while (bits == 0ull) {
                if (w >= 15) return -1;
                bits = sm.r.bmap[clocal * 16 + (++w)];
            }
            const int b = __ffsll((unsigned long long)bits) - 1;
            bits &= bits - 1ull;
            return (w << 6) + b;
        };
        int cur = next();
        float f[16];
        if (cur >= 0) {
            const float* p = df + cur * NDF + dim0;
            const float4 q0 = ((const float4*)p)[0], q1 = ((const float4*)p)[1];
            const float4 q2 = ((const float4*)p)[2], q3 = ((const float4*)p)[3];
            f[0]=q0.x; f[1]=q0.y; f[2]=q0.z; f[3]=q0.w;
            f[4]=q1.x; f[5]=q1.y; f[6]=q1.z; f[7]=q1.w;
            f[8]=q2.x; f[9]=q2.y; f[10]=q2.z; f[11]=q2.w;
            f[12]=q3.x; f[13]=q3.y; f[14]=q3.z; f[15]=q3.w;
        }
        while (cur >= 0) {
            const int nxt = next();
            float g[16];
            if (nxt >= 0) {
                const float* p = df + nxt * NDF + dim0;
                const float4 q0 = ((const float4*)p)[0], q1 = ((const float4*)p)[1];
                const float4 q2 = ((const float4*)p)[2], q3 = ((const float4*)p)[3];
                g[0]=q0.x; g[1]=q0.y; g[2]=q0.z; g[3]=q0.w;
                g[4]=q1.x; g[5]=q1.y; g[6]=q1.z; g[7]=q1.w;
                g[8]=q2.x; g[9]=q2.y; g[10]=q2.z; g[11]=q2.w;
                g[12]=q3.x; g[13]=q3.y; g[14]=q3.z; g[15]=q3.w;
            }
            const float c2 = 1.0f / (nf + 1.0f);
            const float c1 = nf * c2;
            const float c12 = c1 * c2;
#pragma unroll
            for (int j = 0; j < 16; ++j) {
                m[j] = m[j] * c1 + f[j] * c2;     // == f when nf==0
                const float a = f[j] - m[j];
                v[j] = v[j] * c1 + a * a * c12;
            }
            nf += 1.0f;
#pragma unroll
            for (int j = 0; j < 16; ++j) f[j] = g[j];
            cur = nxt;
        }
    } else {
        const int l32 = lane & 31;
        const float* pd = df + bsample * NDF + l32 * 16;
        const float* pf = fc + bt * NDF + l32 * 16;
        float s = 0.f;
#pragma unroll
        for (int i = 0; i < 4; ++i) {
            const float4 dq = ((const float4*)pd)[i];
            const float4 fq = ((const float4*)pf)[i];
            s = fmaf(bf16r(dq.x), bf16r(fq.x), s);
            s = fmaf(bf16r(dq.y), bf16r(fq.y), s);
            s = fmaf(bf16r(dq.z), bf16r(fq.z), s);
            s = fmaf(bf16r(dq.w), bf16r(fq.w), s);
        }
        s += __shfl_xor(s, 1); s += __shfl_xor(s, 2); s += __shfl_xor(s, 4);
        s += __shfl_xor(s, 8); s += __shfl_xor(s, 16);
        if (l32 == 0) bias1[bsample] = s;
    }
    __syncthreads();                                   // S3

    if (wv < 4) {
        char* arow = sm.g.A + sr * 256;
        char* brow = sm.g.B + sr * 256;
        float4 l0, l1, l2, l3;
        l0.x=-2.f*fcq[0]*v[0];  l0.y=-2.f*fcq[1]*v[1];  l0.z=-2.f*fcq[2]*v[2];  l0.w=-2.f*fcq[3]*v[3];
        l1.x=-2.f*fcq[4]*v[4];  l1.y=-2.f*fcq[5]*v[5];  l1.z=-2.f*fcq[6]*v[6];  l1.w=-2.f*fcq[7]*v[7];
        l2.x=-2.f*fcq[8]*v[8];  l2.y=-2.f*fcq[9]*v[9];  l2.z=-2.f*fcq[10]*v[10]; l2.w=-2.f*fcq[11]*v[11];
        l3.x=-2.f*fcq[12]*v[12]; l3.y=-2.f*fcq[13]*v[13]; l3.z=-2.f*fcq[14]*v[14]; l3.w=-2.f*fcq[15]*v[15];
        float4 p0, p1, p2, p3;
        p0.x=v[0];  p0.y=v[1];  p0.z=v[2];  p0.w=v[3];
        p1.x=v[4];  p1.y=v[5];  p1.z=v[6];  p1.w=v[7];
        p2.x=v[8];  p2.y=v[9];  p2.z=v[10]; p2.w=v[11];
        p3.x=v[12]; p3.y=v[13]; p3.z=v[14]; p3.w=v[15];
        float4 s0, s1, s2, s3;
        s0.x=b0.x*b0.x; s0.y=b0.y*b0.y; s0.z=b0.z*b0.z; s0.w=b0.w*b0.w;
        s1.x=b1.x*b1.x; s1.y=b1.y*b1.y; s1.z=b1.z*b1.z; s1.w=b1.w*b1.w;
        s2.x=b2.x*b2.x; s2.y=b2.y*b2.y; s2.z=b2.z*b2.z; s2.w=b2.w*b2.w;
        s3.x=b3.x*b3.x; s3.y=b3.y*b3.y; s3.z=b3.z*b3.z; s3.w=b3.w*b3.w;
        *(uint4*)(arow + ((kbl + 0) ^ sswz)) = pk16(l0, l1);
        *(uint4*)(arow + ((kbl + 16) ^ sswz)) = pk16(l2, l3);
        *(uint4*)(arow + ((kbq + 0) ^ sswz)) = pk16(p0, p1);
        *(uint4*)(arow + ((kbq + 16) ^ sswz)) = pk16(p2, p3);
        *(uint4*)(brow + ((kbl + 0) ^ sswz)) = pk16(b0, b1);
        *(uint4*)(brow + ((kbl + 16) ^ sswz)) = pk16(b2, b3);
        *(uint4*)(brow + ((kbq + 0) ^ sswz)) = pk16(s0, s1);
        *(uint4*)(brow + ((kbq + 16) ^ sswz)) = pk16(s2, s3);
    }
    __syncthreads();                                   // S4

    if (wv < 4) {
        const int fr = lane & 15;
        const int fkb = (lane >> 4) * 16;
        const int fswz = (fr & 7) << 4;
        const int wm = (wv >> 1) * 32, wn = (wv & 1) * 32;
        f32x4 acc[2][2];
        acc[0][0] = 0.f; acc[0][1] = 0.f; acc[1][0] = 0.f; acc[1][1] = 0.f;
#pragma unroll
        for (int st = 0; st < 4; ++st) {
            const int kb = (st * 64 + fkb) ^ fswz;
            const bf16x8 aF0 = *(const bf16x8*)(sm.g.A + (wm + fr) * 256 + kb);
            const bf16x8 aF1 = *(const bf16x8*)(sm.g.A + (wm + 16 + fr) * 256 + kb);
            const bf16x8 bF0 = *(const bf16x8*)(sm.g.B + (wn + fr) * 256 + kb);
            const bf16x8 bF1 = *(const bf16x8*)(sm.g.B + (wn + 16 + fr) * 256 + kb);
            acc[0][0] = __builtin_amdgcn_mfma_f32_16x16x32_bf16(aF0, bF0, acc[0][0], 0, 0, 0);
            acc[0][1] = __builtin_amdgcn_mfma_f32_16x16x32_bf16(aF0, bF1, acc[0][1], 0, 0, 0);
            acc[1][0] = __builtin_amdgcn_mfma_f32_16x16x32_bf16(aF1, bF0, acc[1][0], 0, 0, 0);
            acc[1][1] = __builtin_amdgcn_mfma_f32_16x16x32_bf16(aF1, bF1, acc[1][1], 0, 0, 0);
        }
        float* base = Rp + z * (NCLS * NCLS) + (bm * 64) * NCLS + bn * 64;
#pragma unroll
        for (int mi = 0; mi < 2; ++mi)
#pragma unroll
            for (int ni = 0; ni < 2; ++ni)
#pragma unroll
                for (int r2 = 0; r2 < 4; ++r2)
                    base[(wm + mi * 16 + (lane >> 4) * 4 + r2) * NCLS + wn + ni * 16 + fr] =
                        acc[mi][ni][r2];
    }
}

// ---------------------------------------------------------------------------
// Kernel 2: LDS-FREE. 256 blocks x 256 threads. Block (bm=bid>>3, bn=bid&7):
// 32x32 out tile; wave quadrant (wm,wn) in {0,16}^2. Each lane loads its own
// A/B fragments straight from global (32B each, L2-resident), packs to bf16
// in-register, 16 MFMA in 2 chains. No barriers, no LDS. Fused fold epilogue.
__global__ __launch_bounds__(256) void k2_s1_out(const float* __restrict__ df,
                                                 const int* __restrict__ gt,
                                                 const float* __restrict__ fc,
                                                 const float* __restrict__ Rp,
                                                 const float* __restrict__ bias1,
                                                 float* __restrict__ out) {
    const int tid = threadIdx.x;
    const int bn = blockIdx.x & 7, bm = blockIdx.x >> 3;
    const int lane = tid & 63, wv = tid >> 6;
    const int wm = (wv >> 1) * 16, wn = (wv & 1) * 16;
    const int fr = lane & 15;
    const int ksub = (lane >> 4) * 8;        // dim offset of this lane's 8-elem slice

    // fragment source rows (m89-verified layout: lane l row = l&15, k = (l>>4)*8+j)
    const float* Arow = df + (bm * 32 + wm + fr) * NDF + ksub;
    const float* Brow = fc + (bn * 32 + wn + fr) * NDF + ksub;

    f32x4 accE = 0.f, accO = 0.f;
#pragma unroll
    for (int s = 0; s < 16; s += 2) {
        const float4 a00 = ((const float4*)(Arow + s * 32))[0];
        const float4 a01 = ((const float4*)(Arow + s * 32))[1];
        const float4 b00 = ((const float4*)(Brow + s * 32))[0];
        const float4 b01 = ((const float4*)(Brow + s * 32))[1];
        const float4 a10 = ((const float4*)(Arow + s * 32 + 32))[0];
        const float4 a11 = ((const float4*)(Arow + s * 32 + 32))[1];
        const float4 b10 = ((const float4*)(Brow + s * 32 + 32))[0];
        const float4 b11 = ((const float4*)(Brow + s * 32 + 32))[1];
        accE = __builtin_amdgcn_mfma_f32_16x16x32_bf16(pkfrag(a00, a01), pkfrag(b00, b01), accE, 0, 0, 0);
        accO = __builtin_amdgcn_mfma_f32_16x16x32_bf16(pkfrag(a10, a11), pkfrag(b10, b11), accO, 0, 0, 0);
    }

    // fused epilogue: C row = bm*32+wm+(lane>>4)*4+r, col = bn*32+wn+fr
    const int colg = bn * 32 + wn + fr;
#pragma unroll
    for (int r = 0; r < 4; ++r) {
        const int bg = bm * 32 + wm + (lane >> 4) * 4 + r;
        const int t = gt[bg];                 // broadcast per 16-lane group
        float vR = 0.f, vtt = 0.f;
#pragma unroll
        for (int z = 0; z < 8; ++z) {
            const float* rp = Rp + z * (NCLS * NCLS) + t * NCLS;
            vR += rp[colg];
            vtt += rp[t];
        }
        out[bg * NCLS + colg] = (accE[r] + accO[r] - bias1[bg])
                                + 0.5f * ALP * (vR - vtt);
    }
}

// ---------------------------------------------------------------------------
extern "C" void kernel_launch(void* const* d_in, const int* in_sizes, int n_in,
                              void* d_out, int out_size, void* d_ws, size_t ws_size,
                              hipStream_t stream) {
    const float* df = (const float*)d_in[0];
    const int* gt = (const int*)d_in[1];
    const float* fc = (const float*)d_in[2];
    float* out = (float*)d_out;

    float* ws = (float*)d_ws;
    float* Rp = ws;                            // 8*NCLS*NCLS = 524,288 f (2 MB)
    float* bias1 = Rp + 8 * NCLS * NCLS;       // 1024 f

    k1_R_bias<<<128, 512, 0, stream>>>(df, gt, fc, Rp, bias1);
    k2_s1_out<<<256, 256, 0, stream>>>(df, gt, fc, Rp, bias1, out);
}